// Round 11
// baseline (169.245 us; speedup 1.0000x reference)
//
#include <hip/hip_runtime.h>
#include <hip/hip_bf16.h>

// Problem constants: T=512, B=8, D=512, H=8, DH=64
#define TT 512
#define BB 8
#define DD 512
#define HH 8
#define DHH 64

typedef unsigned short ushort_t;
using frag16 = __attribute__((ext_vector_type(8))) short;     // 8 bf16
using f32x4  = __attribute__((ext_vector_type(4))) float;     // MFMA acc
using usx4   = __attribute__((ext_vector_type(4))) ushort_t;  // 4 bf16

#define MFMA16 __builtin_amdgcn_mfma_f32_16x16x32_bf16

__device__ inline ushort_t f2bf(float x) {
    __hip_bfloat16 h = __float2bfloat16(x);
    ushort_t u; __builtin_memcpy(&u, &h, 2); return u;
}
__device__ inline float bf2f(ushort_t u) {
    __hip_bfloat16 h; __builtin_memcpy(&h, &u, 2);
    return __bfloat162float(h);
}

// async global->LDS DMA, 16 B/lane; lds dest = wave-uniform base + lane*16
__device__ inline void gload16(const void* g, void* l) {
    __builtin_amdgcn_global_load_lds(
        (const __attribute__((address_space(1))) unsigned int*)g,
        (__attribute__((address_space(3))) unsigned int*)l, 16, 0, 0);
}

// ---------------------------------------------------------------------------
// Kernel 1: fused input prep (feat planes, x split, W transpose+split).
// ---------------------------------------------------------------------------
__device__ inline void split_t_tile(const float* __restrict__ in,
                                    ushort_t* __restrict__ oh,
                                    ushort_t* __restrict__ ol,
                                    int K, int N, int bx, int by, int tid,
                                    float (*tile)[33]) {
    int n0 = bx * 32, k0 = by * 32;
    {
        int r = tid >> 3, c0 = (tid & 7) * 4;
        float4 v = *(const float4*)&in[(size_t)(k0 + r) * N + n0 + c0];
        tile[r][c0] = v.x; tile[r][c0 + 1] = v.y;
        tile[r][c0 + 2] = v.z; tile[r][c0 + 3] = v.w;
    }
    __syncthreads();
    {
        int n = tid >> 3, kk = (tid & 7) * 4;
        usx4 H, L;
        #pragma unroll
        for (int t = 0; t < 4; ++t) {
            float x = tile[kk + t][n];
            ushort_t hh = f2bf(x);
            H[t] = hh;
            L[t] = f2bf(x - bf2f(hh));
        }
        *(usx4*)&oh[(size_t)(n0 + n) * K + k0 + kk] = H;
        *(usx4*)&ol[(size_t)(n0 + n) * K + k0 + kk] = L;
    }
}

__global__ __launch_bounds__(256) void prep_kernel(
        const float* __restrict__ x, const float* __restrict__ W_pos,
        const float* __restrict__ W_qkv, const float* __restrict__ W_out,
        ushort_t* __restrict__ fh, ushort_t* __restrict__ fl,
        ushort_t* __restrict__ xh, ushort_t* __restrict__ xl,
        ushort_t* __restrict__ WposT_h, ushort_t* __restrict__ WposT_l,
        ushort_t* __restrict__ WqkvT_h, ushort_t* __restrict__ WqkvT_l,
        ushort_t* __restrict__ WoutT_h, ushort_t* __restrict__ WoutT_l) {
    __shared__ float tile[32][33];
    int blk = blockIdx.x;
    int tid = threadIdx.x;
    if (blk < 512) {                        // feat: 4 consecutive c per thread
        int idx = blk * 1024 + tid * 4;
        int r = idx >> 9, c0 = idx & 511;
        float dist = (float)(r - 511);
        const float nl4 = -logf(10000.0f) / 256.0f;
        usx4 H, L;
        #pragma unroll
        for (int t = 0; t < 4; ++t) {
            int c = c0 + t;
            int cc = c & 255;
            float freq = __expf(nl4 * (float)cc);
            float ang = dist * freq;
            float v = (c < 256) ? __sinf(ang) : __cosf(ang);
            ushort_t hh = f2bf(v);
            H[t] = hh;
            L[t] = f2bf(v - bf2f(hh));
        }
        *(usx4*)&fh[idx] = H;
        *(usx4*)&fl[idx] = L;
    } else if (blk < 2560) {                // split x (4 elems/thread)
        int i = (blk - 512) * 256 + tid;
        float4 v = ((const float4*)x)[i];
        float e[4] = {v.x, v.y, v.z, v.w};
        usx4 H, L;
        #pragma unroll
        for (int t = 0; t < 4; ++t) {
            ushort_t hh = f2bf(e[t]);
            H[t] = hh;
            L[t] = f2bf(e[t] - bf2f(hh));
        }
        ((usx4*)xh)[i] = H;
        ((usx4*)xl)[i] = L;
    } else if (blk < 2816) {                // W_pos^T
        int f = blk - 2560;
        split_t_tile(W_pos, WposT_h, WposT_l, 512, 512, f & 15, f >> 4, tid, tile);
    } else if (blk < 3584) {                // W_qkv^T
        int f = blk - 2816;
        split_t_tile(W_qkv, WqkvT_h, WqkvT_l, 512, 1536, f % 48, f / 48, tid, tile);
    } else {                                // W_out^T
        int f = blk - 3584;
        split_t_tile(W_out, WoutT_h, WoutT_l, 512, 512, f & 15, f >> 4, tid, tile);
    }
}

// ---------------------------------------------------------------------------
// Kernel 2 (device core): split-bf16 MFMA GEMM, single-barrier double-buffered
// pipeline. MODE 0: fp32 C + bias. MODE 1: hi plane + lo plane only for
// n0 < lo_nlim. MODE 2: hi only. MODE 3: hi only, written TRANSPOSED into the
// V^T layout vt[(gm&7)*DD + gn][gm>>3]  (fuses the old vtrans kernel).
// ---------------------------------------------------------------------------
template <int TM, int TN, int MODE>
__device__ void gemm_bf3_dev(
        ushort_t* lds0, ushort_t* lds1, int bx, int by,
        const ushort_t* __restrict__ Ah, const ushort_t* __restrict__ Al,
        const ushort_t* __restrict__ Bh, const ushort_t* __restrict__ Bl,
        const float* __restrict__ bias, float* __restrict__ C,
        ushort_t* __restrict__ Ch, ushort_t* __restrict__ Cl,
        int M, int N, int K, int lo_nlim) {
    constexpr int NMI = TM / 32;
    constexpr int NNI = TN / 32;
    constexpr int NCH = (TM + TN) / 8;

    const int tid = threadIdx.x;
    const int lane = tid & 63;
    const int w = tid >> 6;
    const int wm = w & 1, wn = w >> 1;
    const int c = lane & 15, quad = lane >> 4;
    const int m0 = by * TM;
    const int n0 = bx * TN;
    const bool wlo = (MODE == 1) && (n0 < lo_nlim);

    auto stage = [&](int k0, ushort_t* lds) {
        #pragma unroll
        for (int ci = 0; ci < NCH / 4; ++ci) {
            int ch = ci * 4 + w;               // wave-uniform chunk id
            int cell = ch * 64 + lane;
            const ushort_t* src;
            if (cell < 8 * TM) {
                int plane = cell / (4 * TM);
                int rem = cell - plane * 4 * TM;
                int q = rem / TM, r = rem - q * TM;
                src = (plane ? Al : Ah) + (size_t)(m0 + r) * K + k0 + q * 8;
            } else {
                int cb = cell - 8 * TM;
                int plane = cb / (4 * TN);
                int rem = cb - plane * 4 * TN;
                int q = rem / TN, r = rem - q * TN;
                src = (plane ? Bl : Bh) + (size_t)(n0 + r) * K + k0 + q * 8;
            }
            gload16(src, &lds[(size_t)(ch * 64) * 8]);
        }
    };

    f32x4 acc[NMI][NNI];
    #pragma unroll
    for (int mi = 0; mi < NMI; ++mi)
        #pragma unroll
        for (int ni = 0; ni < NNI; ++ni)
            acc[mi][ni] = (f32x4){0.f, 0.f, 0.f, 0.f};

    const int NIT = K >> 5;
    stage(0, lds0);
    for (int it = 0; it < NIT; ++it) {
        ushort_t* cur = (it & 1) ? lds1 : lds0;
        ushort_t* nxt = (it & 1) ? lds0 : lds1;
        __syncthreads();
        if (it + 1 < NIT) stage((it + 1) * 32, nxt);

        frag16 a_h[NMI], a_l[NMI], b_h[NNI], b_l[NNI];
        #pragma unroll
        for (int mi = 0; mi < NMI; ++mi) {
            int arow = wm * (TM / 2) + mi * 16 + c;
            a_h[mi] = *(const frag16*)&cur[((0 * 4 + quad) * TM + arow) * 8];
            a_l[mi] = *(const frag16*)&cur[((1 * 4 + quad) * TM + arow) * 8];
        }
        #pragma unroll
        for (int ni = 0; ni < NNI; ++ni) {
            int brow = wn * (TN / 2) + ni * 16 + c;
            b_h[ni] = *(const frag16*)&cur[(8 * TM + (0 * 4 + quad) * TN + brow) * 8];
            b_l[ni] = *(const frag16*)&cur[(8 * TM + (1 * 4 + quad) * TN + brow) * 8];
        }
        #pragma unroll
        for (int mi = 0; mi < NMI; ++mi)
            #pragma unroll
            for (int ni = 0; ni < NNI; ++ni) {
                acc[mi][ni] = MFMA16(a_h[mi], b_h[ni], acc[mi][ni], 0, 0, 0);
                acc[mi][ni] = MFMA16(a_h[mi], b_l[ni], acc[mi][ni], 0, 0, 0);
                acc[mi][ni] = MFMA16(a_l[mi], b_h[ni], acc[mi][ni], 0, 0, 0);
            }
    }

    #pragma unroll
    for (int mi = 0; mi < NMI; ++mi)
        #pragma unroll
        for (int ni = 0; ni < NNI; ++ni)
            #pragma unroll
            for (int reg = 0; reg < 4; ++reg) {
                int gm = m0 + wm * (TM / 2) + mi * 16 + quad * 4 + reg;
                int gn = n0 + wn * (TN / 2) + ni * 16 + c;
                float v = acc[mi][ni][reg];
                if (MODE == 0) {
                    C[(size_t)gm * N + gn] = v + bias[gn];
                } else if (MODE == 3) {
                    // V^T layout: row (b*DD + d), col t; gm = t*8 + b, gn = d
                    Ch[((size_t)(gm & 7) * DD + gn) * TT + (gm >> 3)] = f2bf(v);
                } else {
                    ushort_t hh = f2bf(v);
                    Ch[(size_t)gm * N + gn] = hh;
                    if (MODE == 1 && wlo)
                        Cl[(size_t)gm * N + gn] = f2bf(v - bf2f(hh));
                }
            }
}

// fused launch, XCD-ownership swizzle:
//   qkv q+k cols (bn 0..7):  row-major planes (lo only for q cols)
//   qkv v cols   (bn 8..11): TRANSPOSED hi into vt (vtrans fused away)
//   table (128 blocks): hi plane
__global__ __launch_bounds__(256, 2) void big_gemm(
        const ushort_t* __restrict__ x_h, const ushort_t* __restrict__ x_l,
        const ushort_t* __restrict__ WqkvT_h, const ushort_t* __restrict__ WqkvT_l,
        ushort_t* __restrict__ qkv_h, ushort_t* __restrict__ qkv_l,
        ushort_t* __restrict__ vt_h,
        const ushort_t* __restrict__ feat_h, const ushort_t* __restrict__ feat_l,
        const ushort_t* __restrict__ WposT_h, const ushort_t* __restrict__ WposT_l,
        ushort_t* __restrict__ table_h) {
    __shared__ __align__(16) ushort_t lds[2 * 64 * 256];   // 64 KB
    int blk = blockIdx.x;
    if (blk < 384) {
        int xcd = blk & 7, idx = blk >> 3;      // idx in [0,48)
        int bm = xcd * 4 + idx / 12;            // m-tile owned by this XCD
        int bn = idx % 12;
        if (bn < 8) {
            gemm_bf3_dev<128, 128, 1>(lds, lds + 64 * 256, bn, bm,
                                      x_h, x_l, WqkvT_h, WqkvT_l,
                                      nullptr, nullptr, qkv_h, qkv_l,
                                      4096, 1536, 512, 512);   // lo only for q
        } else {
            // V section: B rows 1024.. of WqkvT; output direct to vt
            gemm_bf3_dev<128, 128, 3>(lds, lds + 64 * 256, bn - 8, bm,
                                      x_h, x_l,
                                      WqkvT_h + (size_t)1024 * 512,
                                      WqkvT_l + (size_t)1024 * 512,
                                      nullptr, nullptr, vt_h, nullptr,
                                      4096, 512, 512, 0);
        }
    } else {
        int f = blk - 384;                      // 128 blocks
        int xcd = f & 7, idx = f >> 3;          // idx in [0,16)
        int bm = xcd * 2 + (idx >> 3);          // m-tile in [0,16)
        int bn = idx & 7;
        gemm_bf3_dev<64, 64, 2>(lds, lds + 64 * 128, bn, bm,
                                feat_h, feat_l, WposT_h, WposT_l,
                                nullptr, nullptr, table_h, nullptr,
                                1024, 512, 512, 0);
    }
}

// out-proj: 512 blocks, XCD owns 8 m-tiles (1 MB A) + WoutT (1 MB)
__global__ __launch_bounds__(256, 3) void outproj_gemm(
        const ushort_t* __restrict__ ao_h, const ushort_t* __restrict__ ao_l,
        const ushort_t* __restrict__ WoutT_h, const ushort_t* __restrict__ WoutT_l,
        const float* __restrict__ bias, float* __restrict__ C) {
    __shared__ __align__(16) ushort_t lds[2 * 64 * 128];   // 32 KB
    int blk = blockIdx.x;
    int xcd = blk & 7, idx = blk >> 3;          // idx in [0,64)
    int bm = xcd * 8 + (idx >> 3);              // m-tile in [0,64)
    int bn = idx & 7;
    gemm_bf3_dev<64, 64, 0>(lds, lds + 64 * 128, bn, bm,
                            ao_h, ao_l, WoutT_h, WoutT_l,
                            bias, C, nullptr, nullptr,
                            4096, 512, 512, 0);
}

// ---------------------------------------------------------------------------
// Kernel 3: fused flash attention, split-bf16 MFMA (R9/R10 structure).
// ---------------------------------------------------------------------------
struct WU {
    union {
        float    qp[16][81];
        ushort_t p[16][72];
    };
};

__global__ __launch_bounds__(256, 2) void attn_kernel(
        const ushort_t* __restrict__ qkv_h, const ushort_t* __restrict__ qkv_l,
        const ushort_t* __restrict__ T_h,
        const ushort_t* __restrict__ vt_h,
        const float* __restrict__ pos_u, const float* __restrict__ pos_v,
        const float* __restrict__ tau,
        ushort_t* __restrict__ o_h, ushort_t* __restrict__ o_l) {
    const int b  = blockIdx.x;
    const int i0 = blockIdx.y * 64;
    const int h  = blockIdx.z;
    const int tid  = threadIdx.x;
    const int lane = tid & 63;
    const int w    = tid >> 6;
    const int c    = lane & 15;
    const int quad = lane >> 4;

    __shared__ __align__(16) ushort_t Kbuf[4096];   // 64 K rows, hi only
    __shared__ __align__(16) ushort_t Vbuf[4096];   // 64 V^T rows, hi only
    __shared__ __align__(16) ushort_t Pbuf[8192];   // 128-slot circular window
    __shared__ __align__(16) WU wbuf[4];

    const int chl = (lane & 7) ^ (lane >> 3);       // staging source chunk
    const int rql = lane >> 3;                      // staging row offset
    const int swz0 = quad ^ (c & 7);                // frag chunk, kb=0
    const int swz1 = (4 + quad) ^ (c & 7);          // frag chunk, kb=1

    const float tauexp = expf(tau[0]);
    const float scale  = 0.125f;
    const float NEGMAX = -3.4028234663852886e38f;

    // ---- persistent q fragments (qu = q+u, qv = q+v), hi/lo split ----
    frag16 qu_h[2], qu_l[2], qv_h[2], qv_l[2];
    {
        int row = i0 + w * 16 + c;
        size_t base = ((size_t)row * BB + b) * (3 * DD) + h * DHH;
        const float* up = pos_u + h * DHH;
        const float* vp = pos_v + h * DHH;
        #pragma unroll
        for (int kb = 0; kb < 2; ++kb) {
            int d0 = kb * 32 + quad * 8;
            union { frag16 v; ushort_t s[8]; } QH, QL, UH, UL, VH, VL;
            QH.v = *(const frag16*)&qkv_h[base + d0];
            QL.v = *(const frag16*)&qkv_l[base + d0];
            #pragma unroll
            for (int t = 0; t < 8; ++t) {
                float q = bf2f(QH.s[t]) + bf2f(QL.s[t]);
                float a = q + up[d0 + t];
                ushort_t ah = f2bf(a);
                UH.s[t] = ah; UL.s[t] = f2bf(a - bf2f(ah));
                float bq = q + vp[d0 + t];
                ushort_t bh = f2bf(bq);
                VH.s[t] = bh; VL.s[t] = f2bf(bq - bf2f(bh));
            }
            qu_h[kb] = UH.v; qu_l[kb] = UL.v;
            qv_h[kb] = VH.v; qv_l[kb] = VL.v;
        }
    }

    float m_r[4], l_r[4];
    f32x4 o_acc[4];
    #pragma unroll
    for (int r = 0; r < 4; ++r) { m_r[r] = NEGMAX; l_r[r] = 0.f; }
    #pragma unroll
    for (int d = 0; d < 4; ++d) o_acc[d] = (f32x4){0.f, 0.f, 0.f, 0.f};

    for (int jt = 0; jt < 8; ++jt) {
        const int j0  = jt * 64;
        const int rlo = i0 - j0 + 448;     // window = table rows [rlo, rlo+128)

        __syncthreads();                   // A: prev-iter readers done

        // stage K (hi): 8 DMA issues, 2 per wave
        #pragma unroll
        for (int it = 0; it < 2; ++it) {
            int r0 = (it * 4 + w) * 8;
            const ushort_t* src = qkv_h
                + ((size_t)(j0 + r0 + rql) * BB + b) * (3 * DD) + DD + h * DHH + chl * 8;
            gload16(src, &Kbuf[r0 * 64]);
        }
        // stage V^T (hi): 8 DMA issues, 2 per wave
        #pragma unroll
        for (int it = 0; it < 2; ++it) {
            int r0 = (it * 4 + w) * 8;
            const ushort_t* src = vt_h
                + ((size_t)b * DD + h * DHH + r0 + rql) * TT + j0 + chl * 8;
            gload16(src, &Vbuf[r0 * 64]);
        }
        // stage P window: 128 rows at jt=0, 64 new rows after
        if (jt == 0) {
            #pragma unroll
            for (int it = 0; it < 4; ++it) {
                int r0 = (it * 4 + w) * 8;
                int sbase = (rlo + r0) & 127;
                const ushort_t* src = T_h + (size_t)(rlo + r0 + rql) * DD + h * DHH + chl * 8;
                gload16(src, &Pbuf[sbase * 64]);
            }
        } else {
            #pragma unroll
            for (int it = 0; it < 2; ++it) {
                int r0 = (it * 4 + w) * 8;
                int sbase = (rlo + r0) & 127;
                const ushort_t* src = T_h + (size_t)(rlo + r0 + rql) * DD + h * DHH + chl * 8;
                gload16(src, &Pbuf[sbase * 64]);
            }
        }
        __syncthreads();                   // B: all staging visible

        // ---- QP = qv @ P_band^T (16 x 80): 2 products -> per-wave LDS ----
        f32x4 qp_acc[5];
        #pragma unroll
        for (int rs = 0; rs < 5; ++rs) {
            f32x4 acc = (f32x4){0.f, 0.f, 0.f, 0.f};
            int slot = (rlo + w * 16 + rs * 16 + c) & 127;
            frag16 p0 = *(const frag16*)&Pbuf[slot * 64 + swz0 * 8];
            frag16 p1 = *(const frag16*)&Pbuf[slot * 64 + swz1 * 8];
            acc = MFMA16(qv_h[0], p0, acc, 0, 0, 0);
            acc = MFMA16(qv_l[0], p0, acc, 0, 0, 0);
            acc = MFMA16(qv_h[1], p1, acc, 0, 0, 0);
            acc = MFMA16(qv_l[1], p1, acc, 0, 0, 0);
            qp_acc[rs] = acc;
        }
        #pragma unroll
        for (int rs = 0; rs < 5; ++rs)
            #pragma unroll
            for (int reg = 0; reg < 4; ++reg)
                wbuf[w].qp[quad * 4 + reg][rs * 16 + c] = qp_acc[rs][reg];

        // ---- AC = qu @ K^T (16 x 64): full q x bf16 k ----
        f32x4 ac[4];
        #pragma unroll
        for (int js = 0; js < 4; ++js) {
            f32x4 acc = (f32x4){0.f, 0.f, 0.f, 0.f};
            int krow = js * 16 + c;
            frag16 kh0 = *(const frag16*)&Kbuf[krow * 64 + swz0 * 8];
            frag16 kh1 = *(const frag16*)&Kbuf[krow * 64 + swz1 * 8];
            acc = MFMA16(qu_h[0], kh0, acc, 0, 0, 0);
            acc = MFMA16(qu_l[0], kh0, acc, 0, 0, 0);
            acc = MFMA16(qu_h[1], kh1, acc, 0, 0, 0);
            acc = MFMA16(qu_l[1], kh1, acc, 0, 0, 0);
            ac[js] = acc;
        }

        // ---- energy assembly ----
        float ev[4][4];
        #pragma unroll
        for (int js = 0; js < 4; ++js) {
            int jl = js * 16 + c;
            #pragma unroll
            for (int reg = 0; reg < 4; ++reg) {
                int il = quad * 4 + reg;
                float bd = wbuf[w].qp[il][il - jl + 63];
                float e = (ac[js][reg] + bd) * scale;
                if (i0 + w * 16 + il == j0 + jl) e = NEGMAX;
                ev[js][reg] = e * tauexp;
            }
        }

        // ---- online softmax; p single plane, l from rounded p ----
        float alpha[4], mn[4];
        #pragma unroll
        for (int reg = 0; reg < 4; ++reg) {
            float mx = fmaxf(fmaxf(ev[0][reg], ev[1][reg]),
                             fmaxf(ev[2][reg], ev[3][reg]));
            #pragma unroll
            for (int m = 1; m < 16; m <<= 1) mx = fmaxf(mx, __shfl_xor(mx, m));
            float m2 = fmaxf(m_r[reg], mx);
            alpha[reg] = __expf(m_r[reg] - m2);
            mn[reg] = m2;
            m_r[reg] = m2;
        }
        float ss[4] = {0.f, 0.f, 0.f, 0.f};
        #pragma unroll
        for (int js = 0; js < 4; ++js) {
            int jl = js * 16 + c;
            #pragma unroll
            for (int reg = 0; reg < 4; ++reg) {
                float p = __expf(ev[js][reg] - mn[reg]);
                ushort_t ph = f2bf(p);
                ss[reg] += bf2f(ph);
                wbuf[w].p[quad * 4 + reg][jl] = ph;
            }
        }
        #pragma unroll
        for (int reg = 0; reg < 4; ++reg) {
            float s = ss[reg];
            #pragma unroll
            for (int m = 1; m < 16; m <<= 1) s += __shfl_xor(s, m);
            l_r[reg] = l_r[reg] * alpha[reg] + s;
        }

        // ---- O = O*alpha + p @ V (wave-private wbuf; V staged pre-B) ----
        frag16 pf0 = *(const frag16*)&wbuf[w].p[c][quad * 8];
        frag16 pf1 = *(const frag16*)&wbuf[w].p[c][32 + quad * 8];
        #pragma unroll
        for (int ds = 0; ds < 4; ++ds) {
            f32x4 acc = o_acc[ds];
            #pragma unroll
            for (int reg = 0; reg < 4; ++reg) acc[reg] *= alpha[reg];
            int vrow = ds * 16 + c;
            frag16 vh0 = *(const frag16*)&Vbuf[vrow * 64 + swz0 * 8];
            frag16 vh1 = *(const frag16*)&Vbuf[vrow * 64 + swz1 * 8];
            acc = MFMA16(pf0, vh0, acc, 0, 0, 0);
            acc = MFMA16(pf1, vh1, acc, 0, 0, 0);
            o_acc[ds] = acc;
        }
    }

    // ---- epilogue: normalize (rcp), split, store planes ----
    #pragma unroll
    for (int reg = 0; reg < 4; ++reg)
        l_r[reg] = __builtin_amdgcn_rcpf(l_r[reg]);
    #pragma unroll
    for (int ds = 0; ds < 4; ++ds)
        #pragma unroll
        for (int reg = 0; reg < 4; ++reg) {
            int row = i0 + w * 16 + quad * 4 + reg;
            size_t idx = ((size_t)row * BB + b) * DD + h * DHH + ds * 16 + c;
            float val = o_acc[ds][reg] * l_r[reg];
            ushort_t hh = f2bf(val);
            o_h[idx] = hh;
            o_l[idx] = f2bf(val - bf2f(hh));
        }
}

// ---------------------------------------------------------------------------
// launch (4 kernels)
// ---------------------------------------------------------------------------
extern "C" void kernel_launch(void* const* d_in, const int* in_sizes, int n_in,
                              void* d_out, int out_size, void* d_ws, size_t ws_size,
                              hipStream_t stream) {
    const float* x     = (const float*)d_in[0];
    const float* W_qkv = (const float*)d_in[1];
    const float* W_pos = (const float*)d_in[2];
    const float* pos_u = (const float*)d_in[3];
    const float* pos_v = (const float*)d_in[4];
    const float* W_out = (const float*)d_in[5];
    const float* b_out = (const float*)d_in[6];
    const float* tau   = (const float*)d_in[7];
    float* out = (float*)d_out;

    ushort_t* p = (ushort_t*)d_ws;
    ushort_t* feat_h  = p; p += 1024 * 512;
    ushort_t* feat_l  = p; p += 1024 * 512;
    ushort_t* WposT_h = p; p += 512 * 512;
    ushort_t* WposT_l = p; p += 512 * 512;
    ushort_t* table_h = p; p += 1024 * 512;
    ushort_t* x_h     = p; p += 4096 * 512;
    ushort_t* x_l     = p; p += 4096 * 512;
    ushort_t* WqkvT_h = p; p += 1536 * 512;
    ushort_t* WqkvT_l = p; p += 1536 * 512;
    ushort_t* qkv_h   = p; p += 4096 * 1536;
    ushort_t* qkv_l   = p; p += 4096 * 1536;
    ushort_t* WoutT_h = p; p += 512 * 512;
    ushort_t* WoutT_l = p; p += 512 * 512;
    ushort_t* ao_h    = p; p += 4096 * 512;
    ushort_t* ao_l    = p; p += 4096 * 512;
    ushort_t* vt_h    = p; p += 4096 * 512;   // own buffer (x live in big_gemm)

    // 1. input prep
    prep_kernel<<<3840, 256, 0, stream>>>(
        x, W_pos, W_qkv, W_out, feat_h, feat_l, x_h, x_l,
        WposT_h, WposT_l, WqkvT_h, WqkvT_l, WoutT_h, WoutT_l);
    // 2. qkv GEMM (q+k row-major, V transposed into vt) + table GEMM
    big_gemm<<<512, 256, 0, stream>>>(
        x_h, x_l, WqkvT_h, WqkvT_l, qkv_h, qkv_l, vt_h,
        feat_h, feat_l, WposT_h, WposT_l, table_h);
    // 3. fused attention -> attno planes  (grid: XCD = b)
    attn_kernel<<<dim3(BB, 8, HH), 256, 0, stream>>>(
        qkv_h, qkv_l, table_h, vt_h, pos_u, pos_v, tau, ao_h, ao_l);
    // 4. out = attno @ W_out + b_out  (XCD-swizzled, 512 blocks)
    outproj_gemm<<<512, 256, 0, stream>>>(
        ao_h, ao_l, WoutT_h, WoutT_l, b_out, out);
}

// Round 12
// 157.964 us; speedup vs baseline: 1.0714x; 1.0714x over previous
//
#include <hip/hip_runtime.h>
#include <hip/hip_bf16.h>

// Problem constants: T=512, B=8, D=512, H=8, DH=64
#define TT 512
#define BB 8
#define DD 512
#define HH 8
#define DHH 64

typedef unsigned short ushort_t;
using frag16 = __attribute__((ext_vector_type(8))) short;     // 8 bf16
using f32x4  = __attribute__((ext_vector_type(4))) float;     // MFMA acc
using usx4   = __attribute__((ext_vector_type(4))) ushort_t;  // 4 bf16

#define MFMA16 __builtin_amdgcn_mfma_f32_16x16x32_bf16

__device__ inline ushort_t f2bf(float x) {
    __hip_bfloat16 h = __float2bfloat16(x);
    ushort_t u; __builtin_memcpy(&u, &h, 2); return u;
}
__device__ inline float bf2f(ushort_t u) {
    __hip_bfloat16 h; __builtin_memcpy(&h, &u, 2);
    return __bfloat162float(h);
}

// async global->LDS DMA, 16 B/lane; lds dest = wave-uniform base + lane*16
__device__ inline void gload16(const void* g, void* l) {
    __builtin_amdgcn_global_load_lds(
        (const __attribute__((address_space(1))) unsigned int*)g,
        (__attribute__((address_space(3))) unsigned int*)l, 16, 0, 0);
}

// ---------------------------------------------------------------------------
// Kernel 1: fused input prep (feat planes, x hi-plane, W transpose+split).
// ---------------------------------------------------------------------------
__device__ inline void split_t_tile(const float* __restrict__ in,
                                    ushort_t* __restrict__ oh,
                                    ushort_t* __restrict__ ol,
                                    int K, int N, int bx, int by, int tid,
                                    float (*tile)[33]) {
    int n0 = bx * 32, k0 = by * 32;
    {
        int r = tid >> 3, c0 = (tid & 7) * 4;
        float4 v = *(const float4*)&in[(size_t)(k0 + r) * N + n0 + c0];
        tile[r][c0] = v.x; tile[r][c0 + 1] = v.y;
        tile[r][c0 + 2] = v.z; tile[r][c0 + 3] = v.w;
    }
    __syncthreads();
    {
        int n = tid >> 3, kk = (tid & 7) * 4;
        usx4 H, L;
        #pragma unroll
        for (int t = 0; t < 4; ++t) {
            float x = tile[kk + t][n];
            ushort_t hh = f2bf(x);
            H[t] = hh;
            L[t] = f2bf(x - bf2f(hh));
        }
        *(usx4*)&oh[(size_t)(n0 + n) * K + k0 + kk] = H;
        *(usx4*)&ol[(size_t)(n0 + n) * K + k0 + kk] = L;
    }
}

__global__ __launch_bounds__(256) void prep_kernel(
        const float* __restrict__ x, const float* __restrict__ W_pos,
        const float* __restrict__ W_qkv, const float* __restrict__ W_out,
        ushort_t* __restrict__ fh, ushort_t* __restrict__ fl,
        ushort_t* __restrict__ xh,
        ushort_t* __restrict__ WposT_h, ushort_t* __restrict__ WposT_l,
        ushort_t* __restrict__ WqkvT_h, ushort_t* __restrict__ WqkvT_l,
        ushort_t* __restrict__ WoutT_h, ushort_t* __restrict__ WoutT_l) {
    __shared__ float tile[32][33];
    int blk = blockIdx.x;
    int tid = threadIdx.x;
    if (blk < 512) {                        // feat: 4 consecutive c per thread
        int idx = blk * 1024 + tid * 4;
        int r = idx >> 9, c0 = idx & 511;
        float dist = (float)(r - 511);
        const float nl4 = -logf(10000.0f) / 256.0f;
        usx4 H, L;
        #pragma unroll
        for (int t = 0; t < 4; ++t) {
            int c = c0 + t;
            int cc = c & 255;
            float freq = __expf(nl4 * (float)cc);
            float ang = dist * freq;
            float v = (c < 256) ? __sinf(ang) : __cosf(ang);
            ushort_t hh = f2bf(v);
            H[t] = hh;
            L[t] = f2bf(v - bf2f(hh));
        }
        *(usx4*)&fh[idx] = H;
        *(usx4*)&fl[idx] = L;
    } else if (blk < 2560) {                // x -> hi plane only
        int i = (blk - 512) * 256 + tid;
        float4 v = ((const float4*)x)[i];
        float e[4] = {v.x, v.y, v.z, v.w};
        usx4 H;
        #pragma unroll
        for (int t = 0; t < 4; ++t) H[t] = f2bf(e[t]);
        ((usx4*)xh)[i] = H;
    } else if (blk < 2816) {                // W_pos^T
        int f = blk - 2560;
        split_t_tile(W_pos, WposT_h, WposT_l, 512, 512, f & 15, f >> 4, tid, tile);
    } else if (blk < 3584) {                // W_qkv^T
        int f = blk - 2816;
        split_t_tile(W_qkv, WqkvT_h, WqkvT_l, 512, 1536, f % 48, f / 48, tid, tile);
    } else {                                // W_out^T
        int f = blk - 3584;
        split_t_tile(W_out, WoutT_h, WoutT_l, 512, 512, f & 15, f >> 4, tid, tile);
    }
}

// ---------------------------------------------------------------------------
// Kernel 2 (device core): split-bf16 MFMA GEMM, single-barrier double-buffered
// pipeline. APL = A planes (2: hi+lo, 3 products; 1: hi only, 2 products —
// a_h*(b_h+b_l), B keeps full precision).
// MODE 0: fp32 C + bias. MODE 1: hi plane + lo plane for n0 < lo_nlim.
// MODE 2: hi only.
// Per-buffer LDS cells (8 ushorts each): APL*4*TM (A) + 8*TN (B).
// ---------------------------------------------------------------------------
template <int TM, int TN, int MODE, int APL>
__device__ void gemm_bf3_dev(
        ushort_t* lds0, ushort_t* lds1, int bx, int by,
        const ushort_t* __restrict__ Ah, const ushort_t* __restrict__ Al,
        const ushort_t* __restrict__ Bh, const ushort_t* __restrict__ Bl,
        const float* __restrict__ bias, float* __restrict__ C,
        ushort_t* __restrict__ Ch, ushort_t* __restrict__ Cl,
        int M, int N, int K, int lo_nlim) {
    constexpr int NMI = TM / 32;
    constexpr int NNI = TN / 32;
    constexpr int ACELLS = APL * 4 * TM;
    constexpr int NCH = (ACELLS + 8 * TN) / 64;    // 64-cell (1 KB) chunks

    const int tid = threadIdx.x;
    const int lane = tid & 63;
    const int w = tid >> 6;
    const int wm = w & 1, wn = w >> 1;
    const int c = lane & 15, quad = lane >> 4;
    const int m0 = by * TM;
    const int n0 = bx * TN;
    const bool wlo = (MODE == 1) && (n0 < lo_nlim);

    auto stage = [&](int k0, ushort_t* lds) {
        #pragma unroll
        for (int ci = 0; ci < NCH / 4; ++ci) {
            int ch = ci * 4 + w;               // wave-uniform chunk id
            int cell = ch * 64 + lane;
            const ushort_t* src;
            if (cell < ACELLS) {
                int plane = cell / (4 * TM);
                int rem = cell - plane * 4 * TM;
                int q = rem / TM, r = rem - q * TM;
                src = (plane ? Al : Ah) + (size_t)(m0 + r) * K + k0 + q * 8;
            } else {
                int cb = cell - ACELLS;
                int plane = cb / (4 * TN);
                int rem = cb - plane * 4 * TN;
                int q = rem / TN, r = rem - q * TN;
                src = (plane ? Bl : Bh) + (size_t)(n0 + r) * K + k0 + q * 8;
            }
            gload16(src, &lds[(size_t)(ch * 64) * 8]);
        }
    };

    f32x4 acc[NMI][NNI];
    #pragma unroll
    for (int mi = 0; mi < NMI; ++mi)
        #pragma unroll
        for (int ni = 0; ni < NNI; ++ni)
            acc[mi][ni] = (f32x4){0.f, 0.f, 0.f, 0.f};

    const int NIT = K >> 5;
    stage(0, lds0);
    for (int it = 0; it < NIT; ++it) {
        ushort_t* cur = (it & 1) ? lds1 : lds0;
        ushort_t* nxt = (it & 1) ? lds0 : lds1;
        __syncthreads();
        if (it + 1 < NIT) stage((it + 1) * 32, nxt);

        frag16 a_h[NMI], a_l[NMI], b_h[NNI], b_l[NNI];
        #pragma unroll
        for (int mi = 0; mi < NMI; ++mi) {
            int arow = wm * (TM / 2) + mi * 16 + c;
            a_h[mi] = *(const frag16*)&cur[((0 * 4 + quad) * TM + arow) * 8];
            if (APL == 2)
                a_l[mi] = *(const frag16*)&cur[((4 + quad) * TM + arow) * 8];
        }
        #pragma unroll
        for (int ni = 0; ni < NNI; ++ni) {
            int brow = wn * (TN / 2) + ni * 16 + c;
            b_h[ni] = *(const frag16*)&cur[(ACELLS + (0 * 4 + quad) * TN + brow) * 8];
            b_l[ni] = *(const frag16*)&cur[(ACELLS + (4 + quad) * TN + brow) * 8];
        }
        #pragma unroll
        for (int mi = 0; mi < NMI; ++mi)
            #pragma unroll
            for (int ni = 0; ni < NNI; ++ni) {
                acc[mi][ni] = MFMA16(a_h[mi], b_h[ni], acc[mi][ni], 0, 0, 0);
                acc[mi][ni] = MFMA16(a_h[mi], b_l[ni], acc[mi][ni], 0, 0, 0);
                if (APL == 2)
                    acc[mi][ni] = MFMA16(a_l[mi], b_h[ni], acc[mi][ni], 0, 0, 0);
            }
    }

    #pragma unroll
    for (int mi = 0; mi < NMI; ++mi)
        #pragma unroll
        for (int ni = 0; ni < NNI; ++ni)
            #pragma unroll
            for (int reg = 0; reg < 4; ++reg) {
                int gm = m0 + wm * (TM / 2) + mi * 16 + quad * 4 + reg;
                int gn = n0 + wn * (TN / 2) + ni * 16 + c;
                float v = acc[mi][ni][reg];
                if (MODE == 0) {
                    C[(size_t)gm * N + gn] = v + bias[gn];
                } else {
                    ushort_t hh = f2bf(v);
                    Ch[(size_t)gm * N + gn] = hh;
                    if (MODE == 1 && wlo)
                        Cl[(size_t)gm * N + gn] = f2bf(v - bf2f(hh));
                }
            }
}

// fused launch, XCD-ownership swizzle:
//   qkv (384 blocks, 128x128, A = x hi-only, 2 products)
//   table (128 blocks, 64x64, 3 products)
__global__ __launch_bounds__(256, 2) void big_gemm(
        const ushort_t* __restrict__ x_h,
        const ushort_t* __restrict__ WqkvT_h, const ushort_t* __restrict__ WqkvT_l,
        ushort_t* __restrict__ qkv_h, ushort_t* __restrict__ qkv_l,
        const ushort_t* __restrict__ feat_h, const ushort_t* __restrict__ feat_l,
        const ushort_t* __restrict__ WposT_h, const ushort_t* __restrict__ WposT_l,
        ushort_t* __restrict__ table_h) {
    __shared__ __align__(16) ushort_t lds[2 * 12288];   // 48 KB
    int blk = blockIdx.x;
    if (blk < 384) {
        int xcd = blk & 7, idx = blk >> 3;      // idx in [0,48)
        int bm = xcd * 4 + idx / 12;            // m-tile owned by this XCD
        int bn = idx % 12;
        gemm_bf3_dev<128, 128, 1, 1>(lds, lds + 12288, bn, bm,
                                     x_h, nullptr, WqkvT_h, WqkvT_l,
                                     nullptr, nullptr, qkv_h, qkv_l,
                                     4096, 1536, 512, 512);  // lo only for q
    } else {
        int f = blk - 384;                      // 128 blocks
        int xcd = f & 7, idx = f >> 3;          // idx in [0,16)
        int bm = xcd * 2 + (idx >> 3);          // m-tile in [0,16)
        int bn = idx & 7;
        gemm_bf3_dev<64, 64, 2, 2>(lds, lds + 8192, bn, bm,
                                   feat_h, feat_l, WposT_h, WposT_l,
                                   nullptr, nullptr, table_h, nullptr,
                                   1024, 512, 512, 0);
    }
}

// out-proj: 512 blocks, XCD owns 8 m-tiles (1 MB A) + WoutT (1 MB)
__global__ __launch_bounds__(256, 3) void outproj_gemm(
        const ushort_t* __restrict__ ao_h, const ushort_t* __restrict__ ao_l,
        const ushort_t* __restrict__ WoutT_h, const ushort_t* __restrict__ WoutT_l,
        const float* __restrict__ bias, float* __restrict__ C) {
    __shared__ __align__(16) ushort_t lds[2 * 8192];    // 32 KB
    int blk = blockIdx.x;
    int xcd = blk & 7, idx = blk >> 3;          // idx in [0,64)
    int bm = xcd * 8 + (idx >> 3);              // m-tile in [0,64)
    int bn = idx & 7;
    gemm_bf3_dev<64, 64, 0, 2>(lds, lds + 8192, bn, bm,
                               ao_h, ao_l, WoutT_h, WoutT_l,
                               bias, C, nullptr, nullptr,
                               4096, 512, 512, 0);
}

// ---------------------------------------------------------------------------
// Kernel 3: V transpose (hi plane only) -> VT[b][h*64+d][t].
// ---------------------------------------------------------------------------
__global__ __launch_bounds__(256) void vtrans_kernel(
        const ushort_t* __restrict__ qh, ushort_t* __restrict__ vth) {
    __shared__ ushort_t th[64][68];
    int blk = blockIdx.x;
    int t0 = (blk & 7) * 64;
    int n0 = ((blk >> 3) & 7) * 64;
    int b  = blk >> 6;
    int tid = threadIdx.x;
    {
        int tr = tid >> 2, nq = (tid & 3) * 16;
        size_t src = ((size_t)(t0 + tr) * BB + b) * (3 * DD) + 2 * DD + n0 + nq;
        *(frag16*)&th[tr][nq]     = *(const frag16*)&qh[src];
        *(frag16*)&th[tr][nq + 8] = *(const frag16*)&qh[src + 8];
    }
    __syncthreads();
    {
        int nl = tid >> 2, tq = (tid & 3) * 16;
        union { frag16 v; ushort_t s[8]; } H0, H1;
        #pragma unroll
        for (int t = 0; t < 8; ++t) {
            H0.s[t] = th[tq + t][nl];
            H1.s[t] = th[tq + 8 + t][nl];
        }
        size_t dst = ((size_t)b * DD + n0 + nl) * TT + t0 + tq;
        *(frag16*)&vth[dst]     = H0.v;
        *(frag16*)&vth[dst + 8] = H1.v;
    }
}

// ---------------------------------------------------------------------------
// Kernel 4: fused flash attention, split-bf16 MFMA (R9/R10 structure).
// ---------------------------------------------------------------------------
struct WU {
    union {
        float    qp[16][81];
        ushort_t p[16][72];
    };
};

__global__ __launch_bounds__(256, 2) void attn_kernel(
        const ushort_t* __restrict__ qkv_h, const ushort_t* __restrict__ qkv_l,
        const ushort_t* __restrict__ T_h,
        const ushort_t* __restrict__ vt_h,
        const float* __restrict__ pos_u, const float* __restrict__ pos_v,
        const float* __restrict__ tau,
        ushort_t* __restrict__ o_h, ushort_t* __restrict__ o_l) {
    const int b  = blockIdx.x;
    const int i0 = blockIdx.y * 64;
    const int h  = blockIdx.z;
    const int tid  = threadIdx.x;
    const int lane = tid & 63;
    const int w    = tid >> 6;
    const int c    = lane & 15;
    const int quad = lane >> 4;

    __shared__ __align__(16) ushort_t Kbuf[4096];   // 64 K rows, hi only
    __shared__ __align__(16) ushort_t Vbuf[4096];   // 64 V^T rows, hi only
    __shared__ __align__(16) ushort_t Pbuf[8192];   // 128-slot circular window
    __shared__ __align__(16) WU wbuf[4];

    const int chl = (lane & 7) ^ (lane >> 3);       // staging source chunk
    const int rql = lane >> 3;                      // staging row offset
    const int swz0 = quad ^ (c & 7);                // frag chunk, kb=0
    const int swz1 = (4 + quad) ^ (c & 7);          // frag chunk, kb=1

    const float tauexp = expf(tau[0]);
    const float scale  = 0.125f;
    const float NEGMAX = -3.4028234663852886e38f;

    // ---- persistent q fragments (qu = q+u, qv = q+v), hi/lo split ----
    frag16 qu_h[2], qu_l[2], qv_h[2], qv_l[2];
    {
        int row = i0 + w * 16 + c;
        size_t base = ((size_t)row * BB + b) * (3 * DD) + h * DHH;
        const float* up = pos_u + h * DHH;
        const float* vp = pos_v + h * DHH;
        #pragma unroll
        for (int kb = 0; kb < 2; ++kb) {
            int d0 = kb * 32 + quad * 8;
            union { frag16 v; ushort_t s[8]; } QH, QL, UH, UL, VH, VL;
            QH.v = *(const frag16*)&qkv_h[base + d0];
            QL.v = *(const frag16*)&qkv_l[base + d0];
            #pragma unroll
            for (int t = 0; t < 8; ++t) {
                float q = bf2f(QH.s[t]) + bf2f(QL.s[t]);
                float a = q + up[d0 + t];
                ushort_t ah = f2bf(a);
                UH.s[t] = ah; UL.s[t] = f2bf(a - bf2f(ah));
                float bq = q + vp[d0 + t];
                ushort_t bh = f2bf(bq);
                VH.s[t] = bh; VL.s[t] = f2bf(bq - bf2f(bh));
            }
            qu_h[kb] = UH.v; qu_l[kb] = UL.v;
            qv_h[kb] = VH.v; qv_l[kb] = VL.v;
        }
    }

    float m_r[4], l_r[4];
    f32x4 o_acc[4];
    #pragma unroll
    for (int r = 0; r < 4; ++r) { m_r[r] = NEGMAX; l_r[r] = 0.f; }
    #pragma unroll
    for (int d = 0; d < 4; ++d) o_acc[d] = (f32x4){0.f, 0.f, 0.f, 0.f};

    for (int jt = 0; jt < 8; ++jt) {
        const int j0  = jt * 64;
        const int rlo = i0 - j0 + 448;     // window = table rows [rlo, rlo+128)

        __syncthreads();                   // A: prev-iter readers done

        // stage K (hi): 8 DMA issues, 2 per wave
        #pragma unroll
        for (int it = 0; it < 2; ++it) {
            int r0 = (it * 4 + w) * 8;
            const ushort_t* src = qkv_h
                + ((size_t)(j0 + r0 + rql) * BB + b) * (3 * DD) + DD + h * DHH + chl * 8;
            gload16(src, &Kbuf[r0 * 64]);
        }
        // stage V^T (hi): 8 DMA issues, 2 per wave
        #pragma unroll
        for (int it = 0; it < 2; ++it) {
            int r0 = (it * 4 + w) * 8;
            const ushort_t* src = vt_h
                + ((size_t)b * DD + h * DHH + r0 + rql) * TT + j0 + chl * 8;
            gload16(src, &Vbuf[r0 * 64]);
        }
        // stage P window: 128 rows at jt=0, 64 new rows after
        if (jt == 0) {
            #pragma unroll
            for (int it = 0; it < 4; ++it) {
                int r0 = (it * 4 + w) * 8;
                int sbase = (rlo + r0) & 127;
                const ushort_t* src = T_h + (size_t)(rlo + r0 + rql) * DD + h * DHH + chl * 8;
                gload16(src, &Pbuf[sbase * 64]);
            }
        } else {
            #pragma unroll
            for (int it = 0; it < 2; ++it) {
                int r0 = (it * 4 + w) * 8;
                int sbase = (rlo + r0) & 127;
                const ushort_t* src = T_h + (size_t)(rlo + r0 + rql) * DD + h * DHH + chl * 8;
                gload16(src, &Pbuf[sbase * 64]);
            }
        }
        __syncthreads();                   // B: all staging visible

        // ---- QP = qv @ P_band^T (16 x 80): 2 products -> per-wave LDS ----
        f32x4 qp_acc[5];
        #pragma unroll
        for (int rs = 0; rs < 5; ++rs) {
            f32x4 acc = (f32x4){0.f, 0.f, 0.f, 0.f};
            int slot = (rlo + w * 16 + rs * 16 + c) & 127;
            frag16 p0 = *(const frag16*)&Pbuf[slot * 64 + swz0 * 8];
            frag16 p1 = *(const frag16*)&Pbuf[slot * 64 + swz1 * 8];
            acc = MFMA16(qv_h[0], p0, acc, 0, 0, 0);
            acc = MFMA16(qv_l[0], p0, acc, 0, 0, 0);
            acc = MFMA16(qv_h[1], p1, acc, 0, 0, 0);
            acc = MFMA16(qv_l[1], p1, acc, 0, 0, 0);
            qp_acc[rs] = acc;
        }
        #pragma unroll
        for (int rs = 0; rs < 5; ++rs)
            #pragma unroll
            for (int reg = 0; reg < 4; ++reg)
                wbuf[w].qp[quad * 4 + reg][rs * 16 + c] = qp_acc[rs][reg];

        // ---- AC = qu @ K^T (16 x 64): full q x bf16 k ----
        f32x4 ac[4];
        #pragma unroll
        for (int js = 0; js < 4; ++js) {
            f32x4 acc = (f32x4){0.f, 0.f, 0.f, 0.f};
            int krow = js * 16 + c;
            frag16 kh0 = *(const frag16*)&Kbuf[krow * 64 + swz0 * 8];
            frag16 kh1 = *(const frag16*)&Kbuf[krow * 64 + swz1 * 8];
            acc = MFMA16(qu_h[0], kh0, acc, 0, 0, 0);
            acc = MFMA16(qu_l[0], kh0, acc, 0, 0, 0);
            acc = MFMA16(qu_h[1], kh1, acc, 0, 0, 0);
            acc = MFMA16(qu_l[1], kh1, acc, 0, 0, 0);
            ac[js] = acc;
        }

        // ---- energy assembly ----
        float ev[4][4];
        #pragma unroll
        for (int js = 0; js < 4; ++js) {
            int jl = js * 16 + c;
            #pragma unroll
            for (int reg = 0; reg < 4; ++reg) {
                int il = quad * 4 + reg;
                float bd = wbuf[w].qp[il][il - jl + 63];
                float e = (ac[js][reg] + bd) * scale;
                if (i0 + w * 16 + il == j0 + jl) e = NEGMAX;
                ev[js][reg] = e * tauexp;
            }
        }

        // ---- online softmax; p single plane, l from rounded p ----
        float alpha[4], mn[4];
        #pragma unroll
        for (int reg = 0; reg < 4; ++reg) {
            float mx = fmaxf(fmaxf(ev[0][reg], ev[1][reg]),
                             fmaxf(ev[2][reg], ev[3][reg]));
            #pragma unroll
            for (int m = 1; m < 16; m <<= 1) mx = fmaxf(mx, __shfl_xor(mx, m));
            float m2 = fmaxf(m_r[reg], mx);
            alpha[reg] = __expf(m_r[reg] - m2);
            mn[reg] = m2;
            m_r[reg] = m2;
        }
        float ss[4] = {0.f, 0.f, 0.f, 0.f};
        #pragma unroll
        for (int js = 0; js < 4; ++js) {
            int jl = js * 16 + c;
            #pragma unroll
            for (int reg = 0; reg < 4; ++reg) {
                float p = __expf(ev[js][reg] - mn[reg]);
                ushort_t ph = f2bf(p);
                ss[reg] += bf2f(ph);
                wbuf[w].p[quad * 4 + reg][jl] = ph;
            }
        }
        #pragma unroll
        for (int reg = 0; reg < 4; ++reg) {
            float s = ss[reg];
            #pragma unroll
            for (int m = 1; m < 16; m <<= 1) s += __shfl_xor(s, m);
            l_r[reg] = l_r[reg] * alpha[reg] + s;
        }

        // ---- O = O*alpha + p @ V (wave-private wbuf; V staged pre-B) ----
        frag16 pf0 = *(const frag16*)&wbuf[w].p[c][quad * 8];
        frag16 pf1 = *(const frag16*)&wbuf[w].p[c][32 + quad * 8];
        #pragma unroll
        for (int ds = 0; ds < 4; ++ds) {
            f32x4 acc = o_acc[ds];
            #pragma unroll
            for (int reg = 0; reg < 4; ++reg) acc[reg] *= alpha[reg];
            int vrow = ds * 16 + c;
            frag16 vh0 = *(const frag16*)&Vbuf[vrow * 64 + swz0 * 8];
            frag16 vh1 = *(const frag16*)&Vbuf[vrow * 64 + swz1 * 8];
            acc = MFMA16(pf0, vh0, acc, 0, 0, 0);
            acc = MFMA16(pf1, vh1, acc, 0, 0, 0);
            o_acc[ds] = acc;
        }
    }

    // ---- epilogue: normalize (rcp), split, store planes ----
    #pragma unroll
    for (int reg = 0; reg < 4; ++reg)
        l_r[reg] = __builtin_amdgcn_rcpf(l_r[reg]);
    #pragma unroll
    for (int ds = 0; ds < 4; ++ds)
        #pragma unroll
        for (int reg = 0; reg < 4; ++reg) {
            int row = i0 + w * 16 + quad * 4 + reg;
            size_t idx = ((size_t)row * BB + b) * DD + h * DHH + ds * 16 + c;
            float val = o_acc[ds][reg] * l_r[reg];
            ushort_t hh = f2bf(val);
            o_h[idx] = hh;
            o_l[idx] = f2bf(val - bf2f(hh));
        }
}

// ---------------------------------------------------------------------------
// launch (5 kernels)
// ---------------------------------------------------------------------------
extern "C" void kernel_launch(void* const* d_in, const int* in_sizes, int n_in,
                              void* d_out, int out_size, void* d_ws, size_t ws_size,
                              hipStream_t stream) {
    const float* x     = (const float*)d_in[0];
    const float* W_qkv = (const float*)d_in[1];
    const float* W_pos = (const float*)d_in[2];
    const float* pos_u = (const float*)d_in[3];
    const float* pos_v = (const float*)d_in[4];
    const float* W_out = (const float*)d_in[5];
    const float* b_out = (const float*)d_in[6];
    const float* tau   = (const float*)d_in[7];
    float* out = (float*)d_out;

    ushort_t* p = (ushort_t*)d_ws;
    ushort_t* feat_h  = p; p += 1024 * 512;
    ushort_t* feat_l  = p; p += 1024 * 512;
    ushort_t* WposT_h = p; p += 512 * 512;
    ushort_t* WposT_l = p; p += 512 * 512;
    ushort_t* table_h = p; p += 1024 * 512;
    ushort_t* x_h     = p; p += 4096 * 512;   // reused as VT_h after big_gemm
    ushort_t* WqkvT_h = p; p += 1536 * 512;
    ushort_t* WqkvT_l = p; p += 1536 * 512;
    ushort_t* qkv_h   = p; p += 4096 * 1536;
    ushort_t* qkv_l   = p; p += 4096 * 1536;
    ushort_t* WoutT_h = p; p += 512 * 512;
    ushort_t* WoutT_l = p; p += 512 * 512;
    ushort_t* ao_h    = p; p += 4096 * 512;
    ushort_t* ao_l    = p; p += 4096 * 512;
    ushort_t* vt_h    = x_h;                  // x_h dead after big_gemm

    // 1. input prep
    prep_kernel<<<3840, 256, 0, stream>>>(
        x, W_pos, W_qkv, W_out, feat_h, feat_l, x_h,
        WposT_h, WposT_l, WqkvT_h, WqkvT_l, WoutT_h, WoutT_l);
    // 2. qkv GEMM (2-product, x hi-only) + table GEMM, XCD-swizzled
    big_gemm<<<512, 256, 0, stream>>>(
        x_h, WqkvT_h, WqkvT_l, qkv_h, qkv_l,
        feat_h, feat_l, WposT_h, WposT_l, table_h);
    // 3. V transpose (hi plane only; overwrites x_h)
    vtrans_kernel<<<512, 256, 0, stream>>>(qkv_h, vt_h);
    // 4. fused attention -> attno planes  (grid: XCD = b)
    attn_kernel<<<dim3(BB, 8, HH), 256, 0, stream>>>(
        qkv_h, qkv_l, table_h, vt_h, pos_u, pos_v, tau, ao_h, ao_l);
    // 5. out = attno @ W_out + b_out  (XCD-swizzled, 512 blocks)
    outproj_gemm<<<512, 256, 0, stream>>>(
        ao_h, ao_l, WoutT_h, WoutT_l, b_out, out);
}